// Round 13
// baseline (347.563 us; speedup 1.0000x reference)
//
#include <hip/hip_runtime.h>
#include <hip/hip_fp16.h>

typedef unsigned short u16;
typedef unsigned int   u32;
typedef unsigned char  u8;
typedef __attribute__((ext_vector_type(8))) short short8;
typedef __attribute__((ext_vector_type(8))) unsigned short ushort8v;
typedef __attribute__((ext_vector_type(4))) float f32x4;

#define TPB 256

#define GLDS16(g,l) __builtin_amdgcn_global_load_lds( \
    (const __attribute__((address_space(1))) void*)(g), \
    (__attribute__((address_space(3))) void*)(l), 16, 0, 0)

__device__ __forceinline__ float b2f(u16 u){ u32 x=((u32)u)<<16; return __uint_as_float(x); }
__device__ __forceinline__ u16 f2b(float f){ u32 x=__float_as_uint(f); u32 r=x+0x7FFFu+((x>>16)&1u); return (u16)(r>>16); }
__device__ __forceinline__ float lrelu(float x){ return x>0.f?x:0.2f*x; }
__device__ __forceinline__ float sigm(float x){ return 1.f/(1.f+__expf(-x)); }

__device__ __forceinline__ float4 ld4(const void* p, size_t i4, int isbf){
  if(isbf){
    ushort4 u=((const ushort4*)p)[i4];
    return make_float4(b2f(u.x),b2f(u.y),b2f(u.z),b2f(u.w));
  }
  return ((const float4*)p)[i4];
}
__device__ __forceinline__ float ld1(const void* p, size_t i, int isbf){
  return isbf ? b2f(((const u16*)p)[i]) : ((const float*)p)[i];
}

// ---------------- FUSED: k_deg (blocks 0..D-1) ∪ k_prep (rest) ----------------
// deg/prep are independent until k_alpha; fusing overlaps deg's atomic-latency phase
// with prep's streaming copy. Prep blocks re-derive isbf locally (flag[0] is written
// by deg-block-0 in the SAME launch, so they can't read it).
__global__ __launch_bounds__(256) void k_build(const int* __restrict__ dst, int E, int N,
    int* __restrict__ deg, int* __restrict__ pos, int* __restrict__ ainv,
    const u16* __restrict__ w0, int* __restrict__ flag,
    const void* __restrict__ Wa, u16* __restrict__ WTa,
    const void* __restrict__ Wb, u16* __restrict__ WTb,
    const void* __restrict__ X, u16* __restrict__ xb, int n8, int D){
  __shared__ int sd[256];
  __shared__ float ts[64][65];
  int bid=blockIdx.x, t=threadIdx.x;
  if(bid<D){
    int gid=bid*256+t;
    if(bid==0){
      int sane=0;
      for(int i=t;i<512;i+=256){
        u16 u=w0[i]; u32 e2=(u>>7)&0xFFu;
        if((e2>=103u&&e2<=143u)||((u&0x7FFFu)==0u)) sane++;
      }
      sd[t]=sane; __syncthreads();
      for(int o=128;o;o>>=1){ if(t<o) sd[t]+=sd[t+o]; __syncthreads(); }
      if(t==0) flag[0]=(sd[0]>=480)?1:0;
    }
    if(gid<N) ainv[gid]=-1;
    if(gid>=E+N) return;
    int d=(gid<E)?dst[gid]:(gid-E);
    d=min(max(d,0),N-1);
    pos[gid]=atomicAdd(&deg[d],1);
    return;
  }
  // ---- prep region: local isbf detect (same reduction as block 0) ----
  {
    int sane=0;
    for(int i=t;i<512;i+=256){
      u16 u=w0[i]; u32 e2=(u>>7)&0xFFu;
      if((e2>=103u&&e2<=143u)||((u&0x7FFFu)==0u)) sane++;
    }
    sd[t]=sane; __syncthreads();
    for(int o=128;o;o>>=1){ if(t<o) sd[t]+=sd[t+o]; __syncthreads(); }
  }
  const int isbf=(sd[0]>=480)?1:0;
  __syncthreads();
  int pbid=bid-D;
  if(pbid<32){
    int z=pbid>>4, y=(pbid>>2)&3, xq=pbid&3;
    const void* W = z ? Wb : Wa;
    u16* WT = z ? WTb : WTa;
    int tx=t&63, ty=t>>6;
    int k0=xq*64, n0=y*64;
    #pragma unroll
    for(int i=0;i<64;i+=4)
      ts[ty+i][tx]=ld1(W,(size_t)(k0+ty+i)*256+n0+tx,isbf);
    __syncthreads();
    #pragma unroll
    for(int i=0;i<64;i+=4)
      WT[(size_t)(n0+ty+i)*256+k0+tx]=f2b(ts[tx][ty+i]);
    return;
  }
  int i=(pbid-32)*256+t; if(i>=n8) return;
  size_t e=(size_t)i*8;
  if(isbf){
    *(ushort8v*)(xb+e)=*(const ushort8v*)((const u16*)X+e);
  }else{
    const float4* fp=(const float4*)((const float*)X+e);
    float4 f0=fp[0], f1=fp[1];
    ushort8v o;
    o[0]=f2b(f0.x); o[1]=f2b(f0.y); o[2]=f2b(f0.z); o[3]=f2b(f0.w);
    o[4]=f2b(f1.x); o[5]=f2b(f1.y); o[6]=f2b(f1.z); o[7]=f2b(f1.w);
    *(ushort8v*)(xb+e)=o;
  }
}

__global__ void k_scan(const int* __restrict__ deg, int* __restrict__ rs,
                       int* __restrict__ counter, int n,
                       const int* __restrict__ aidx, int* __restrict__ ainv, int na){
  __shared__ int tmp[TPB];
  __shared__ int base;
  int i=blockIdx.x*TPB+threadIdx.x;
  if(i<na){ int a=aidx[i]; if(a>=0&&a<n) ainv[a]=i; }
  int v=(i<n)?deg[i]:0;
  tmp[threadIdx.x]=v; __syncthreads();
  for(int off=1;off<TPB;off<<=1){
    int t=(threadIdx.x>=off)?tmp[threadIdx.x-off]:0;
    __syncthreads();
    tmp[threadIdx.x]+=t;
    __syncthreads();
  }
  if(threadIdx.x==TPB-1) base=atomicAdd(counter,tmp[TPB-1]);
  __syncthreads();
  if(i<n) rs[i]=base+tmp[threadIdx.x]-v;
}

// ---------------- FUSED: gemm layer-0 (blocks 0..G-1) ∪ k_fill (rest) ----------------
// fill needs rs (post-scan); gemm0 needs xb (from k_build) — independent of each other.
// GEMM blocks lead the grid so MFMA work seizes CUs; latency-bound fill blocks backfill.
__global__ __launch_bounds__(256) void k_fillgemm(
    const int* __restrict__ src, const int* __restrict__ dstp, int E, int N,
    const int* __restrict__ rs, const int* __restrict__ pos, int* __restrict__ col,
    const u16* __restrict__ A, const u16* __restrict__ BT, u16* __restrict__ C, int M, int G){
  __shared__ short As[128*64];
  __shared__ short Bs[128*64];
  int bid=blockIdx.x;
  const int t=threadIdx.x;
  if(bid>=G){
    int e=(bid-G)*256+t; if(e>=E+N) return;
    int d,s;
    if(e<E){ d=dstp[e]; s=src[e]; } else { d=e-E; s=e-E; }
    d=min(max(d,0),N-1); s=min(max(s,0),N-1);
    col[rs[d]+pos[e]]=s;
    return;
  }
  const int lane=t&63, wv=t>>6;
  const int wm=wv>>1, wn=wv&1;
  const int m15=lane&15, kg=lane>>4;
  const int gm0=(bid>>1)*128, n0=(bid&1)*128;
  const int sr=lane>>3, slot=lane&7;
  f32x4 acc[4][4]={};
  for(int k0=0;k0<256;k0+=64){
    #pragma unroll
    for(int i=0;i<4;++i){
      int r=wv*32+i*8+sr;
      int kq=slot^(r&7);
      int ga=gm0+r; ga=ga<M?ga:M-1;
      GLDS16(A+(size_t)ga*256+k0+kq*8, As+(wv*32+i*8)*64);
      GLDS16(BT+(size_t)(n0+r)*256+k0+kq*8, Bs+(wv*32+i*8)*64);
    }
    __syncthreads();
    #pragma unroll
    for(int s=0;s<2;++s){
      short8 af[4], bf[4];
      #pragma unroll
      for(int mi=0;mi<4;++mi){
        int row=wm*64+mi*16+m15;
        int sl=(s*4+kg)^(row&7);
        af[mi]=*(const short8*)&As[row*64+sl*8];
      }
      #pragma unroll
      for(int ni=0;ni<4;++ni){
        int row=wn*64+ni*16+m15;
        int sl=(s*4+kg)^(row&7);
        bf[ni]=*(const short8*)&Bs[row*64+sl*8];
      }
      #pragma unroll
      for(int mi=0;mi<4;++mi)
        #pragma unroll
        for(int ni=0;ni<4;++ni)
          acc[mi][ni]=__builtin_amdgcn_mfma_f32_16x16x32_bf16(af[mi],bf[ni],acc[mi][ni],0,0,0);
    }
    __syncthreads();
  }
  #pragma unroll
  for(int mi=0;mi<4;++mi){
    #pragma unroll
    for(int r=0;r<4;++r){
      int grow=gm0+wm*64+mi*16+kg*4+r;
      if(grow<M){
        #pragma unroll
        for(int ni=0;ni<4;++ni){
          int gcol=n0+wn*64+ni*16+m15;
          C[(size_t)grow*256+gcol]=f2b(acc[mi][ni][r]);
        }
      }
    }
  }
}

// ---------------- MFMA GEMM, BK=64 (standalone, layer 1) ----------------
__global__ __launch_bounds__(256) void k_gemm(const u16* __restrict__ A, const u16* __restrict__ BT,
                                              u16* __restrict__ C, int M){
  __shared__ short As[128*64];
  __shared__ short Bs[128*64];
  const int t=threadIdx.x;
  const int lane=t&63, wv=t>>6;
  const int wm=wv>>1, wn=wv&1;
  const int m15=lane&15, kg=lane>>4;
  const int gm0=blockIdx.x*128, n0=blockIdx.y*128;
  const int sr=lane>>3, slot=lane&7;
  f32x4 acc[4][4]={};
  for(int k0=0;k0<256;k0+=64){
    #pragma unroll
    for(int i=0;i<4;++i){
      int r=wv*32+i*8+sr;
      int kq=slot^(r&7);
      int ga=gm0+r; ga=ga<M?ga:M-1;
      GLDS16(A+(size_t)ga*256+k0+kq*8, As+(wv*32+i*8)*64);
      GLDS16(BT+(size_t)(n0+r)*256+k0+kq*8, Bs+(wv*32+i*8)*64);
    }
    __syncthreads();
    #pragma unroll
    for(int s=0;s<2;++s){
      short8 af[4], bf[4];
      #pragma unroll
      for(int mi=0;mi<4;++mi){
        int row=wm*64+mi*16+m15;
        int sl=(s*4+kg)^(row&7);
        af[mi]=*(const short8*)&As[row*64+sl*8];
      }
      #pragma unroll
      for(int ni=0;ni<4;++ni){
        int row=wn*64+ni*16+m15;
        int sl=(s*4+kg)^(row&7);
        bf[ni]=*(const short8*)&Bs[row*64+sl*8];
      }
      #pragma unroll
      for(int mi=0;mi<4;++mi)
        #pragma unroll
        for(int ni=0;ni<4;++ni)
          acc[mi][ni]=__builtin_amdgcn_mfma_f32_16x16x32_bf16(af[mi],bf[ni],acc[mi][ni],0,0,0);
    }
    __syncthreads();
  }
  #pragma unroll
  for(int mi=0;mi<4;++mi){
    #pragma unroll
    for(int r=0;r<4;++r){
      int grow=gm0+wm*64+mi*16+kg*4+r;
      if(grow<M){
        #pragma unroll
        for(int ni=0;ni<4;++ni){
          int gcol=n0+wn*64+ni*16+m15;
          C[(size_t)grow*256+gcol]=f2b(acc[mi][ni][r]);
        }
      }
    }
  }
}

// ---------------- attention logits per node + int8(per-row scale) copy of xl ----------------
__global__ __launch_bounds__(256) void k_att(const u16* __restrict__ xl, const void* __restrict__ as_,
                                             const void* __restrict__ ad_, float4* __restrict__ asv,
                                             float2* __restrict__ adv, u8* __restrict__ xl8,
                                             int n, const int* __restrict__ flag){
  const int isbf=flag[0];
  int w=(blockIdx.x*256+threadIdx.x)>>6;
  int lane=threadIdx.x&63;
  if(w>=n) return;
  int ch=lane*4;
  ushort4 u=*(const ushort4*)(xl+(size_t)w*256+ch);
  float4 s=ld4(as_,ch>>2,isbf);
  float4 d=ld4(ad_,ch>>2,isbf);
  float x0=b2f(u.x),x1=b2f(u.y),x2=b2f(u.z),x3=b2f(u.w);
  float m=fmaxf(fmaxf(fabsf(x0),fabsf(x1)),fmaxf(fabsf(x2),fabsf(x3)));
  for(int off=32;off;off>>=1) m=fmaxf(m,__shfl_xor(m,off));
  float mm=fmaxf(m,1e-20f);
  float scale=mm*(1.f/127.f);
  float rsc=127.f/mm;
  int q0=(int)rintf(fmaf(x0,rsc,128.f));
  int q1=(int)rintf(fmaf(x1,rsc,128.f));
  int q2=(int)rintf(fmaf(x2,rsc,128.f));
  int q3=(int)rintf(fmaf(x3,rsc,128.f));
  u32 pack=(u32)q0|((u32)q1<<8)|((u32)q2<<16)|((u32)q3<<24);
  ((u32*)(xl8+(size_t)w*256))[lane]=pack;
  float ps=x0*s.x+x1*s.y+x2*s.z+x3*s.w;
  float pd=x0*d.x+x1*d.y+x2*d.z+x3*d.w;
  for(int off=16;off;off>>=1){ ps+=__shfl_xor(ps,off); pd+=__shfl_xor(pd,off); }
  float ps1=__shfl(ps,32), pd1=__shfl(pd,32);
  if(lane==0){
    asv[w]=make_float4(ps,ps1,scale,0.f);
    adv[w]=make_float2(pd,pd1);
  }
}

// ---------------- per-edge softmax weights (HALF-WAVE per dst) + per-dst denominators ----------------
__global__ __launch_bounds__(256) void k_alpha(const int* __restrict__ rs, const int* __restrict__ deg,
    const int* __restrict__ col, const float4* __restrict__ asv, const float2* __restrict__ adv,
    int2* __restrict__ ew, float2* __restrict__ rden, int n){
  int w=(blockIdx.x*256+threadIdx.x)>>5;
  int lane=threadIdx.x&31;
  if(w>=n) return;
  int s0=rs[w], cnt=deg[w];
  float2 ad=adv[w];
  float sum0=0.f, sum1=0.f;
  for(int base=0;base<cnt;base+=32){
    int j=base+lane;
    if(j<cnt){
      int sv=col[s0+j];
      float4 a=asv[sv];
      float e0=fminf(lrelu(a.x+ad.x),11.f);   // clamp: keep exp finite in f16
      float e1=fminf(lrelu(a.y+ad.y),11.f);
      float w0=__expf(e0), w1=__expf(e1);
      sum0+=w0; sum1+=w1;
      __half2 p=__floats2half2_rn(w0*a.z,w1*a.z);
      ew[s0+j]=make_int2(sv,*(int*)&p);
    }
  }
  for(int off=16;off;off>>=1){ sum0+=__shfl_xor(sum0,off); sum1+=__shfl_xor(sum1,off); }
  if(lane==0) rden[w]=make_float2(1.f/(sum0+1e-16f),1.f/(sum1+1e-16f));
}

// ---------------- weighted aggregation: HALF-WAVE per dst, int8 row gather ----------------
// 4-edge groups, double-buffered (A/B) — r12 structure (neutral-positive). Accumulation
// order is edge-index ascending, identical noise class to the passing builds.
__global__ __launch_bounds__(256) void k_agg(const int* __restrict__ rs, const int* __restrict__ deg,
    const int2* __restrict__ ew, const float2* __restrict__ rden,
    const u8* __restrict__ xl8, const void* __restrict__ bias,
    u16* __restrict__ hout, void* __restrict__ out, int ostride, int ocol,
    const int* __restrict__ ainv, int n, const int* __restrict__ flag){
  const int isbf=flag[0];
  int w=(blockIdx.x*blockDim.x+threadIdx.x)>>5;   // one 32-lane half-wave per dst
  int sl=threadIdx.x&31;
  if(w>=n) return;
  int s0=rs[w], cnt=deg[w];
  int ch=sl*8, h=sl>>4;
  float acc[8]={};
  float sumw=0.f;
  int2 eA[4]; uint2 rA[4];
  int2 eB[4]; uint2 rB[4];
#define LOADG(e_,r_,J) do{ \
    _Pragma("unroll") \
    for(int u=0;u<4;++u){ int idx=(J)+u; idx=idx<cnt?idx:cnt-1; e_[u]=ew[s0+idx]; } \
    _Pragma("unroll") \
    for(int u=0;u<4;++u) r_[u]=*(const uint2*)(xl8+(size_t)e_[u].x*256+ch); \
  }while(0)
#define COMPG(e_,r_,J) do{ \
    _Pragma("unroll") \
    for(int u=0;u<4;++u){ \
      __half2 p=*(__half2*)&e_[u].y; \
      float wb=__half2float(h?__high2half(p):__low2half(p)); \
      wb=((J)+u<cnt)?wb:0.f; \
      u32 a=r_[u].x, b=r_[u].y; \
      acc[0]=fmaf(wb,(float)( a     &255u),acc[0]); \
      acc[1]=fmaf(wb,(float)((a>> 8)&255u),acc[1]); \
      acc[2]=fmaf(wb,(float)((a>>16)&255u),acc[2]); \
      acc[3]=fmaf(wb,(float)( a>>24      ),acc[3]); \
      acc[4]=fmaf(wb,(float)( b     &255u),acc[4]); \
      acc[5]=fmaf(wb,(float)((b>> 8)&255u),acc[5]); \
      acc[6]=fmaf(wb,(float)((b>>16)&255u),acc[6]); \
      acc[7]=fmaf(wb,(float)( b>>24      ),acc[7]); \
      sumw+=wb; \
    } \
  }while(0)
  LOADG(eA,rA,0);
  int j=0;
  while(j<cnt){
    LOADG(eB,rB,j+4);      // prefetch next group while computing current
    COMPG(eA,rA,j);
    j+=4;
    if(j>=cnt) break;
    LOADG(eA,rA,j+4);
    COMPG(eB,rB,j);
    j+=4;
  }
#undef LOADG
#undef COMPG
  float2 rd=rden[w];
  float rh=h?rd.y:rd.x;
  float4 b0=ld4(bias,ch>>2,isbf);
  float4 b1=ld4(bias,(ch>>2)+1,isbf);
  float c=128.f*sumw;
  float r[8];
  r[0]=sigm((acc[0]-c)*rh+b0.x); r[1]=sigm((acc[1]-c)*rh+b0.y);
  r[2]=sigm((acc[2]-c)*rh+b0.z); r[3]=sigm((acc[3]-c)*rh+b0.w);
  r[4]=sigm((acc[4]-c)*rh+b1.x); r[5]=sigm((acc[5]-c)*rh+b1.y);
  r[6]=sigm((acc[6]-c)*rh+b1.z); r[7]=sigm((acc[7]-c)*rh+b1.w);
  ushort8v ov;
  #pragma unroll
  for(int q=0;q<8;++q) ov[q]=f2b(r[q]);
  if(hout) *(ushort8v*)(hout+(size_t)w*256+ch)=ov;
  int ar=ainv[w];
  if(ar>=0){
    size_t o=(size_t)ar*ostride+ocol+ch;
    if(isbf){
      *(ushort8v*)((u16*)out+o)=ov;
    }else{
      *(float4*)((float*)out+o)  =make_float4(r[0],r[1],r[2],r[3]);
      *(float4*)((float*)out+o+4)=make_float4(r[4],r[5],r[6],r[7]);
    }
  }
}

extern "C" void kernel_launch(void* const* d_in, const int* in_sizes, int n_in,
                              void* d_out, int out_size, void* d_ws, size_t ws_size,
                              hipStream_t stream) {
  const void* x   = d_in[0];
  const int*  ei  = (const int*)d_in[1];
  const int*  aidx= (const int*)d_in[3];
  const void* W0  = d_in[4];
  const void* as0 = d_in[5];
  const void* ad0 = d_in[6];
  const void* b0  = d_in[7];
  const void* W1  = d_in[8];
  const void* as1 = d_in[9];
  const void* ad1 = d_in[10];
  const void* b1  = d_in[11];

  const int N  = in_sizes[0]/256;
  const int E  = in_sizes[1]/2;
  const int na = in_sizes[3];
  const int Et = E+N;

  char* ws=(char*)d_ws; size_t off=0;
  auto alloc=[&](size_t bytes)->void*{ void* p=ws+off; off+=(bytes+255)&~(size_t)255; return p; };
  int*   flg =(int*) alloc(256);
  u16*   xl  =(u16*) alloc((size_t)N*256*2);
  u16*   h1  =(u16*) alloc((size_t)N*256*2);   // doubles as xb (x in bf16): dead before k_agg writes h1
  u8*    xl8 =(u8*)  alloc((size_t)N*256);
  u16*   WT0 =(u16*) alloc((size_t)256*256*2);
  u16*   WT1 =(u16*) alloc((size_t)256*256*2);
  float4* asv=(float4*)alloc((size_t)N*16);
  float2* adv=(float2*)alloc((size_t)N*8);
  char*  zbase=ws+off;
  int*   deg =(int*) alloc((size_t)N*4);
  int*   ctr =(int*) alloc(256);
  size_t zlen=(ws+off)-zbase;
  int*   pos =(int*) alloc((size_t)Et*4);
  int*   rstp=(int*) alloc((size_t)N*4);
  int*   ainv=(int*) alloc((size_t)N*4);
  int*   col =(int*) alloc((size_t)Et*4);
  int2*  ew  =(int2*)alloc((size_t)Et*8);
  float2* rdn=(float2*)alloc((size_t)N*8);

  u16* xb = h1;   // alias (see above)

  const int* esrc=ei;
  const int* edst=ei+E;

  hipMemsetAsync(zbase,0,zlen,stream);

  const int D = (Et+255)/256;                 // deg blocks
  const int P = 32+(N*32+255)/256;            // prep blocks (transpose + copy)
  k_build<<<D+P,256,0,stream>>>(edst,E,N,deg,pos,ainv,(const u16*)W0,flg,
                                W0,WT0,W1,WT1,x,xb,N*32,D);
  k_scan <<<(N+TPB-1)/TPB,TPB,0,stream>>>(deg,rstp,ctr,N,aidx,ainv,na);

  const int G2 = ((N+127)/128)*2;             // gemm blocks (leading)
  const int F  = (Et+255)/256;                // fill blocks (trailing)
  // layer 0: fill ∪ gemm0
  k_fillgemm<<<G2+F,256,0,stream>>>(esrc,edst,E,N,rstp,pos,col,xb,WT0,xl,N,G2);
  k_att  <<<(N+3)/4,256,0,stream>>>(xl,as0,ad0,asv,adv,xl8,N,flg);
  k_alpha<<<(N+7)/8,256,0,stream>>>(rstp,deg,col,asv,adv,ew,rdn,N);
  k_agg  <<<(N+7)/8,256,0,stream>>>(rstp,deg,ew,rdn,xl8,b0,h1,d_out,512,0,ainv,N,flg);
  // layer 1
  dim3 gg((N+127)/128,2);
  k_gemm <<<gg,256,0,stream>>>(h1,WT1,xl,N);
  k_att  <<<(N+3)/4,256,0,stream>>>(xl,as1,ad1,asv,adv,xl8,N,flg);
  k_alpha<<<(N+7)/8,256,0,stream>>>(rstp,deg,col,asv,adv,ew,rdn,N);
  k_agg  <<<(N+7)/8,256,0,stream>>>(rstp,deg,ew,rdn,xl8,b1,(u16*)nullptr,d_out,512,256,ainv,N,flg);
}

// Round 15
// 335.028 us; speedup vs baseline: 1.0374x; 1.0374x over previous
//
#include <hip/hip_runtime.h>
#include <hip/hip_fp16.h>

typedef unsigned short u16;
typedef unsigned int   u32;
typedef unsigned char  u8;
typedef __attribute__((ext_vector_type(8))) short short8;
typedef __attribute__((ext_vector_type(8))) unsigned short ushort8v;
typedef __attribute__((ext_vector_type(4))) float f32x4;

#define TPB 256

#define GLDS16(g,l) __builtin_amdgcn_global_load_lds( \
    (const __attribute__((address_space(1))) void*)(g), \
    (__attribute__((address_space(3))) void*)(l), 16, 0, 0)

__device__ __forceinline__ float b2f(u16 u){ u32 x=((u32)u)<<16; return __uint_as_float(x); }
__device__ __forceinline__ u16 f2b(float f){ u32 x=__float_as_uint(f); u32 r=x+0x7FFFu+((x>>16)&1u); return (u16)(r>>16); }
__device__ __forceinline__ float lrelu(float x){ return x>0.f?x:0.2f*x; }
__device__ __forceinline__ float sigm(float x){ return 1.f/(1.f+__expf(-x)); }

__device__ __forceinline__ float4 ld4(const void* p, size_t i4, int isbf){
  if(isbf){
    ushort4 u=((const ushort4*)p)[i4];
    return make_float4(b2f(u.x),b2f(u.y),b2f(u.z),b2f(u.w));
  }
  return ((const float4*)p)[i4];
}
__device__ __forceinline__ float ld1(const void* p, size_t i, int isbf){
  return isbf ? b2f(((const u16*)p)[i]) : ((const float*)p)[i];
}

// ---------------- FUSED (LDS-free roles only): deg atomics ∥ x->bf16 copy ----------------
// r13 lesson: static LDS poisons latency-bound blocks' occupancy. Here every block is
// LDS-light (1KB detect buffer). Each thread: issue 16B copy load -> edge atomic -> stores;
// the streaming copy hides in the atomic latency shadow. pos[] = atomicAdd return = rank.
__global__ __launch_bounds__(256) void k_deg(const int* __restrict__ dst, int E, int N,
    int* __restrict__ deg, int* __restrict__ pos, int* __restrict__ ainv,
    const u16* __restrict__ w0, int* __restrict__ flag,
    const void* __restrict__ X, u16* __restrict__ xb, int n8){
  __shared__ int sd[256];
  int t=threadIdx.x;
  int gid=blockIdx.x*256+t;
  // wire-dtype detect (all blocks; w0 head is L2-hot after first arrivals)
  int sane=0;
  for(int i=t;i<512;i+=256){
    u16 u=w0[i]; u32 e2=(u>>7)&0xFFu;
    if((e2>=103u&&e2<=143u)||((u&0x7FFFu)==0u)) sane++;
  }
  sd[t]=sane; __syncthreads();
  for(int o=128;o;o>>=1){ if(t<o) sd[t]+=sd[t+o]; __syncthreads(); }
  const int isbf=(sd[0]>=480)?1:0;
  if(gid==0) flag[0]=isbf;
  if(gid<N) ainv[gid]=-1;
  // copy loads issued before the atomic (independent; compiler interleaves)
  const bool docopy = gid<n8;
  size_t e8=(size_t)gid*8;
  ushort8v cv; float4 f0,f1;
  if(docopy){
    if(isbf) cv=*(const ushort8v*)((const u16*)X+e8);
    else { const float4* fp=(const float4*)((const float*)X+e8); f0=fp[0]; f1=fp[1]; }
  }
  if(gid<E+N){
    int d=(gid<E)?dst[gid]:(gid-E);
    d=min(max(d,0),N-1);
    pos[gid]=atomicAdd(&deg[d],1);
  }
  if(docopy){
    if(isbf){
      *(ushort8v*)(xb+e8)=cv;
    }else{
      ushort8v o;
      o[0]=f2b(f0.x); o[1]=f2b(f0.y); o[2]=f2b(f0.z); o[3]=f2b(f0.w);
      o[4]=f2b(f1.x); o[5]=f2b(f1.y); o[6]=f2b(f1.z); o[7]=f2b(f1.w);
      *(ushort8v*)(xb+e8)=o;
    }
  }
}

// ---------------- scan (blocks 0..SB-1) ∪ W transpose (blocks SB..SB+31) ----------------
// scan grid is <=1 block/CU, so the 17KB transpose tile can't cost scan occupancy.
__global__ __launch_bounds__(256) void k_scan(const int* __restrict__ deg, int* __restrict__ rs,
                       int* __restrict__ counter, int n,
                       const int* __restrict__ aidx, int* __restrict__ ainv, int na, int SB,
                       const void* __restrict__ Wa, u16* __restrict__ WTa,
                       const void* __restrict__ Wb, u16* __restrict__ WTb,
                       const int* __restrict__ flag){
  __shared__ int tmp[TPB];
  __shared__ int base;
  __shared__ float s[64][65];
  int bid=blockIdx.x;
  if(bid>=SB){
    const int isbf=flag[0];
    int pbid=bid-SB;
    int z=pbid>>4, y=(pbid>>2)&3, xq=pbid&3;
    const void* W = z ? Wb : Wa;
    u16* WT = z ? WTb : WTa;
    int tx=threadIdx.x&63, ty=threadIdx.x>>6;
    int k0=xq*64, n0=y*64;
    #pragma unroll
    for(int i=0;i<64;i+=4)
      s[ty+i][tx]=ld1(W,(size_t)(k0+ty+i)*256+n0+tx,isbf);
    __syncthreads();
    #pragma unroll
    for(int i=0;i<64;i+=4)
      WT[(size_t)(n0+ty+i)*256+k0+tx]=f2b(s[tx][ty+i]);
    return;
  }
  int i=bid*TPB+threadIdx.x;
  if(i<na){ int a=aidx[i]; if(a>=0&&a<n) ainv[a]=i; }
  int v=(i<n)?deg[i]:0;
  tmp[threadIdx.x]=v; __syncthreads();
  for(int off=1;off<TPB;off<<=1){
    int t=(threadIdx.x>=off)?tmp[threadIdx.x-off]:0;
    __syncthreads();
    tmp[threadIdx.x]+=t;
    __syncthreads();
  }
  if(threadIdx.x==TPB-1) base=atomicAdd(counter,tmp[TPB-1]);
  __syncthreads();
  if(i<n) rs[i]=base+tmp[threadIdx.x]-v;
}

// atomic-free: rank comes from pos[] (computed in k_deg); pure gather + scatter.
__global__ void k_fill(const int* __restrict__ src, const int* __restrict__ dst, int E, int N,
                       const int* __restrict__ rs, const int* __restrict__ pos,
                       int* __restrict__ col){
  int e=blockIdx.x*blockDim.x+threadIdx.x; if(e>=E+N) return;
  int d,s;
  if(e<E){ d=dst[e]; s=src[e]; } else { d=e-E; s=e-E; }
  d=min(max(d,0),N-1); s=min(max(s,0),N-1);
  col[rs[d]+pos[e]]=s;
}

// ---------------- MFMA GEMM, BK=64: C[M,256] = A[M,256] @ B, A bf16, BT = B^T bf16 ----------------
__global__ __launch_bounds__(256) void k_gemm(const u16* __restrict__ A, const u16* __restrict__ BT,
                                              u16* __restrict__ C, int M){
  __shared__ short As[128*64];
  __shared__ short Bs[128*64];
  const int t=threadIdx.x;
  const int lane=t&63, wv=t>>6;
  const int wm=wv>>1, wn=wv&1;
  const int m15=lane&15, kg=lane>>4;
  const int gm0=blockIdx.x*128, n0=blockIdx.y*128;
  const int sr=lane>>3, slot=lane&7;
  f32x4 acc[4][4]={};
  for(int k0=0;k0<256;k0+=64){
    #pragma unroll
    for(int i=0;i<4;++i){
      int r=wv*32+i*8+sr;
      int kq=slot^(r&7);
      int ga=gm0+r; ga=ga<M?ga:M-1;
      GLDS16(A+(size_t)ga*256+k0+kq*8, As+(wv*32+i*8)*64);
      GLDS16(BT+(size_t)(n0+r)*256+k0+kq*8, Bs+(wv*32+i*8)*64);
    }
    __syncthreads();
    #pragma unroll
    for(int s=0;s<2;++s){
      short8 af[4], bf[4];
      #pragma unroll
      for(int mi=0;mi<4;++mi){
        int row=wm*64+mi*16+m15;
        int sl=(s*4+kg)^(row&7);
        af[mi]=*(const short8*)&As[row*64+sl*8];
      }
      #pragma unroll
      for(int ni=0;ni<4;++ni){
        int row=wn*64+ni*16+m15;
        int sl=(s*4+kg)^(row&7);
        bf[ni]=*(const short8*)&Bs[row*64+sl*8];
      }
      #pragma unroll
      for(int mi=0;mi<4;++mi)
        #pragma unroll
        for(int ni=0;ni<4;++ni)
          acc[mi][ni]=__builtin_amdgcn_mfma_f32_16x16x32_bf16(af[mi],bf[ni],acc[mi][ni],0,0,0);
    }
    __syncthreads();
  }
  #pragma unroll
  for(int mi=0;mi<4;++mi){
    #pragma unroll
    for(int r=0;r<4;++r){
      int grow=gm0+wm*64+mi*16+kg*4+r;
      if(grow<M){
        #pragma unroll
        for(int ni=0;ni<4;++ni){
          int gcol=n0+wn*64+ni*16+m15;
          C[(size_t)grow*256+gcol]=f2b(acc[mi][ni][r]);
        }
      }
    }
  }
}

// ---------------- attention logits per node + int8(per-row scale) copy of xl ----------------
__global__ __launch_bounds__(256) void k_att(const u16* __restrict__ xl, const void* __restrict__ as_,
                                             const void* __restrict__ ad_, float4* __restrict__ asv,
                                             float2* __restrict__ adv, u8* __restrict__ xl8,
                                             int n, const int* __restrict__ flag){
  const int isbf=flag[0];
  int w=(blockIdx.x*256+threadIdx.x)>>6;
  int lane=threadIdx.x&63;
  if(w>=n) return;
  int ch=lane*4;
  ushort4 u=*(const ushort4*)(xl+(size_t)w*256+ch);
  float4 s=ld4(as_,ch>>2,isbf);
  float4 d=ld4(ad_,ch>>2,isbf);
  float x0=b2f(u.x),x1=b2f(u.y),x2=b2f(u.z),x3=b2f(u.w);
  float m=fmaxf(fmaxf(fabsf(x0),fabsf(x1)),fmaxf(fabsf(x2),fabsf(x3)));
  for(int off=32;off;off>>=1) m=fmaxf(m,__shfl_xor(m,off));
  float mm=fmaxf(m,1e-20f);
  float scale=mm*(1.f/127.f);
  float rsc=127.f/mm;
  int q0=(int)rintf(fmaf(x0,rsc,128.f));
  int q1=(int)rintf(fmaf(x1,rsc,128.f));
  int q2=(int)rintf(fmaf(x2,rsc,128.f));
  int q3=(int)rintf(fmaf(x3,rsc,128.f));
  u32 pack=(u32)q0|((u32)q1<<8)|((u32)q2<<16)|((u32)q3<<24);
  ((u32*)(xl8+(size_t)w*256))[lane]=pack;
  float ps=x0*s.x+x1*s.y+x2*s.z+x3*s.w;
  float pd=x0*d.x+x1*d.y+x2*d.z+x3*d.w;
  for(int off=16;off;off>>=1){ ps+=__shfl_xor(ps,off); pd+=__shfl_xor(pd,off); }
  float ps1=__shfl(ps,32), pd1=__shfl(pd,32);
  if(lane==0){
    asv[w]=make_float4(ps,ps1,scale,0.f);
    adv[w]=make_float2(pd,pd1);
  }
}

// ---------------- per-edge softmax weights (HALF-WAVE per dst) + per-dst denominators ----------------
__global__ __launch_bounds__(256) void k_alpha(const int* __restrict__ rs, const int* __restrict__ deg,
    const int* __restrict__ col, const float4* __restrict__ asv, const float2* __restrict__ adv,
    int2* __restrict__ ew, float2* __restrict__ rden, int n){
  int w=(blockIdx.x*256+threadIdx.x)>>5;
  int lane=threadIdx.x&31;
  if(w>=n) return;
  int s0=rs[w], cnt=deg[w];
  float2 ad=adv[w];
  float sum0=0.f, sum1=0.f;
  for(int base=0;base<cnt;base+=32){
    int j=base+lane;
    if(j<cnt){
      int sv=col[s0+j];
      float4 a=asv[sv];
      float e0=fminf(lrelu(a.x+ad.x),11.f);   // clamp: keep exp finite in f16
      float e1=fminf(lrelu(a.y+ad.y),11.f);
      float w0=__expf(e0), w1=__expf(e1);
      sum0+=w0; sum1+=w1;
      __half2 p=__floats2half2_rn(w0*a.z,w1*a.z);
      ew[s0+j]=make_int2(sv,*(int*)&p);
    }
  }
  for(int off=16;off;off>>=1){ sum0+=__shfl_xor(sum0,off); sum1+=__shfl_xor(sum1,off); }
  if(lane==0) rden[w]=make_float2(1.f/(sum0+1e-16f),1.f/(sum1+1e-16f));
}

// ---------------- weighted aggregation: HALF-WAVE per dst, int8 row gather ----------------
// 4-edge groups, double-buffered (A/B) — r12 structure. Accumulation order is edge-index
// ascending, identical noise class to the passing builds.
__global__ __launch_bounds__(256) void k_agg(const int* __restrict__ rs, const int* __restrict__ deg,
    const int2* __restrict__ ew, const float2* __restrict__ rden,
    const u8* __restrict__ xl8, const void* __restrict__ bias,
    u16* __restrict__ hout, void* __restrict__ out, int ostride, int ocol,
    const int* __restrict__ ainv, int n, const int* __restrict__ flag){
  const int isbf=flag[0];
  int w=(blockIdx.x*blockDim.x+threadIdx.x)>>5;   // one 32-lane half-wave per dst
  int sl=threadIdx.x&31;
  if(w>=n) return;
  int s0=rs[w], cnt=deg[w];
  int ch=sl*8, h=sl>>4;
  float acc[8]={};
  float sumw=0.f;
  int2 eA[4]; uint2 rA[4];
  int2 eB[4]; uint2 rB[4];
#define LOADG(e_,r_,J) do{ \
    _Pragma("unroll") \
    for(int u=0;u<4;++u){ int idx=(J)+u; idx=idx<cnt?idx:cnt-1; e_[u]=ew[s0+idx]; } \
    _Pragma("unroll") \
    for(int u=0;u<4;++u) r_[u]=*(const uint2*)(xl8+(size_t)e_[u].x*256+ch); \
  }while(0)
#define COMPG(e_,r_,J) do{ \
    _Pragma("unroll") \
    for(int u=0;u<4;++u){ \
      __half2 p=*(__half2*)&e_[u].y; \
      float wb=__half2float(h?__high2half(p):__low2half(p)); \
      wb=((J)+u<cnt)?wb:0.f; \
      u32 a=r_[u].x, b=r_[u].y; \
      acc[0]=fmaf(wb,(float)( a     &255u),acc[0]); \
      acc[1]=fmaf(wb,(float)((a>> 8)&255u),acc[1]); \
      acc[2]=fmaf(wb,(float)((a>>16)&255u),acc[2]); \
      acc[3]=fmaf(wb,(float)( a>>24      ),acc[3]); \
      acc[4]=fmaf(wb,(float)( b     &255u),acc[4]); \
      acc[5]=fmaf(wb,(float)((b>> 8)&255u),acc[5]); \
      acc[6]=fmaf(wb,(float)((b>>16)&255u),acc[6]); \
      acc[7]=fmaf(wb,(float)( b>>24      ),acc[7]); \
      sumw+=wb; \
    } \
  }while(0)
  LOADG(eA,rA,0);
  int j=0;
  while(j<cnt){
    LOADG(eB,rB,j+4);      // prefetch next group while computing current
    COMPG(eA,rA,j);
    j+=4;
    if(j>=cnt) break;
    LOADG(eA,rA,j+4);
    COMPG(eB,rB,j);
    j+=4;
  }
#undef LOADG
#undef COMPG
  float2 rd=rden[w];
  float rh=h?rd.y:rd.x;
  float4 b0=ld4(bias,ch>>2,isbf);
  float4 b1=ld4(bias,(ch>>2)+1,isbf);
  float c=128.f*sumw;
  float r[8];
  r[0]=sigm((acc[0]-c)*rh+b0.x); r[1]=sigm((acc[1]-c)*rh+b0.y);
  r[2]=sigm((acc[2]-c)*rh+b0.z); r[3]=sigm((acc[3]-c)*rh+b0.w);
  r[4]=sigm((acc[4]-c)*rh+b1.x); r[5]=sigm((acc[5]-c)*rh+b1.y);
  r[6]=sigm((acc[6]-c)*rh+b1.z); r[7]=sigm((acc[7]-c)*rh+b1.w);
  ushort8v ov;
  #pragma unroll
  for(int q=0;q<8;++q) ov[q]=f2b(r[q]);
  if(hout) *(ushort8v*)(hout+(size_t)w*256+ch)=ov;
  int ar=ainv[w];
  if(ar>=0){
    size_t o=(size_t)ar*ostride+ocol+ch;
    if(isbf){
      *(ushort8v*)((u16*)out+o)=ov;
    }else{
      *(float4*)((float*)out+o)  =make_float4(r[0],r[1],r[2],r[3]);
      *(float4*)((float*)out+o+4)=make_float4(r[4],r[5],r[6],r[7]);
    }
  }
}

extern "C" void kernel_launch(void* const* d_in, const int* in_sizes, int n_in,
                              void* d_out, int out_size, void* d_ws, size_t ws_size,
                              hipStream_t stream) {
  const void* x   = d_in[0];
  const int*  ei  = (const int*)d_in[1];
  const int*  aidx= (const int*)d_in[3];
  const void* W0  = d_in[4];
  const void* as0 = d_in[5];
  const void* ad0 = d_in[6];
  const void* b0  = d_in[7];
  const void* W1  = d_in[8];
  const void* as1 = d_in[9];
  const void* ad1 = d_in[10];
  const void* b1  = d_in[11];

  const int N  = in_sizes[0]/256;
  const int E  = in_sizes[1]/2;
  const int na = in_sizes[3];
  const int Et = E+N;

  char* ws=(char*)d_ws; size_t off=0;
  auto alloc=[&](size_t bytes)->void*{ void* p=ws+off; off+=(bytes+255)&~(size_t)255; return p; };
  int*   flg =(int*) alloc(256);
  u16*   xl  =(u16*) alloc((size_t)N*256*2);
  u16*   h1  =(u16*) alloc((size_t)N*256*2);   // doubles as xb (x in bf16): dead before k_agg writes h1
  u8*    xl8 =(u8*)  alloc((size_t)N*256);
  u16*   WT0 =(u16*) alloc((size_t)256*256*2);
  u16*   WT1 =(u16*) alloc((size_t)256*256*2);
  float4* asv=(float4*)alloc((size_t)N*16);
  float2* adv=(float2*)alloc((size_t)N*8);
  char*  zbase=ws+off;
  int*   deg =(int*) alloc((size_t)N*4);
  int*   ctr =(int*) alloc(256);
  size_t zlen=(ws+off)-zbase;
  int*   pos =(int*) alloc((size_t)Et*4);
  int*   rstp=(int*) alloc((size_t)N*4);
  int*   ainv=(int*) alloc((size_t)N*4);
  int*   col =(int*) alloc((size_t)Et*4);
  int2*  ew  =(int2*)alloc((size_t)Et*8);
  float2* rdn=(float2*)alloc((size_t)N*8);

  u16* xb = h1;   // alias (see above)

  const int* esrc=ei;
  const int* edst=ei+E;

  hipMemsetAsync(zbase,0,zlen,stream);

  const int n8 = N*32;
  const int GD = ((n8>Et?n8:Et)+255)/256;     // covers both edge range and copy range
  k_deg <<<GD,256,0,stream>>>(edst,E,N,deg,pos,ainv,(const u16*)W0,flg,x,xb,n8);

  const int SB = (N+TPB-1)/TPB;
  k_scan<<<SB+32,TPB,0,stream>>>(deg,rstp,ctr,N,aidx,ainv,na,SB,W0,WT0,W1,WT1,flg);
  k_fill<<<(Et+255)/256,256,0,stream>>>(esrc,edst,E,N,rstp,pos,col);

  dim3 gg((N+127)/128,2);
  // layer 0
  k_gemm <<<gg,256,0,stream>>>(xb,WT0,xl,N);
  k_att  <<<(N+3)/4,256,0,stream>>>(xl,as0,ad0,asv,adv,xl8,N,flg);
  k_alpha<<<(N+7)/8,256,0,stream>>>(rstp,deg,col,asv,adv,ew,rdn,N);
  k_agg  <<<(N+7)/8,256,0,stream>>>(rstp,deg,ew,rdn,xl8,b0,h1,d_out,512,0,ainv,N,flg);
  // layer 1
  k_gemm <<<gg,256,0,stream>>>(h1,WT1,xl,N);
  k_att  <<<(N+3)/4,256,0,stream>>>(xl,as1,ad1,asv,adv,xl8,N,flg);
  k_alpha<<<(N+7)/8,256,0,stream>>>(rstp,deg,col,asv,adv,ew,rdn,N);
  k_agg  <<<(N+7)/8,256,0,stream>>>(rstp,deg,ew,rdn,xl8,b1,(u16*)nullptr,d_out,512,256,ainv,N,flg);
}